// Round 7
// baseline (346.700 us; speedup 1.0000x reference)
//
#include <hip/hip_runtime.h>
#include <cstdint>
#include <cstddef>

#define DEVI __device__ __forceinline__

typedef __bf16 bf16x8 __attribute__((ext_vector_type(8)));
typedef float floatx4 __attribute__((ext_vector_type(4)));
typedef unsigned short us4v __attribute__((ext_vector_type(4)));
typedef unsigned short us8 __attribute__((ext_vector_type(8)));

static_assert(sizeof(bf16x8) == 16, "bf16x8 must be 16B");
static_assert(sizeof(us8) == 16, "us8 must be 16B");

// ---------------- helpers ----------------

#if __has_builtin(__builtin_amdgcn_cvt_pk_bf16_f32)
DEVI unsigned short f2bf(float f) {
  typedef __bf16 bf16x2 __attribute__((ext_vector_type(2)));
  union { bf16x2 v; unsigned short u[2]; } c;
  c.v = __builtin_amdgcn_cvt_pk_bf16_f32(f, 0.f);
  return c.u[0];
}
#else
DEVI unsigned short f2bf(float f) {
  unsigned int u = __float_as_uint(f);
  u += 0x7fffu + ((u >> 16) & 1u);   // RNE
  return (unsigned short)(u >> 16);
}
#endif

DEVI float exp2c(float x) {
#if __has_builtin(__builtin_amdgcn_exp2f)
  return __builtin_amdgcn_exp2f(x);
#else
  return exp2f(x);
#endif
}

DEVI bf16x8 ld8(const unsigned short* p) { return *(const bf16x8*)p; }

typedef const __attribute__((address_space(1))) void* gas_ptr;
typedef __attribute__((address_space(3))) void* las_ptr;

DEVI void gld16(const void* g, void* l) {
  __builtin_amdgcn_global_load_lds((gas_ptr)g, (las_ptr)l, 16, 0, 0);
}

#define WAIT_LGKM0() __builtin_amdgcn_s_waitcnt(0xc07f)   // lgkmcnt(0) only
#define WAIT_VM12()  __builtin_amdgcn_s_waitcnt(0x0f7c)   // vmcnt(12) only
#define WAIT_VM0()   __builtin_amdgcn_s_waitcnt(0x0f70)   // vmcnt(0) only
#define SB()         __builtin_amdgcn_sched_barrier(0)

// ---- relaxed-poll grid barrier (R6-proven correct; fences only at edges) ----
DEVI void grid_bar(unsigned int* cnt, unsigned int target, int tid) {
  __syncthreads();
  if (tid == 0) {
    __threadfence();   // release: flush this block's global writes (wbl2)
    __hip_atomic_fetch_add(cnt, 1u, __ATOMIC_RELAXED, __HIP_MEMORY_SCOPE_AGENT);
    while (__hip_atomic_load(cnt, __ATOMIC_RELAXED, __HIP_MEMORY_SCOPE_AGENT) < target)
      __builtin_amdgcn_s_sleep(32);
    __threadfence();   // acquire: invalidate stale caches once
  }
  __syncthreads();
}

// ================= kernel 1: prep + QKV GEMM (768 blocks, >=3 blocks/CU) =================
// Phase A: prep (mask pack / cvt / weight transpose), 10624 units grid-strided.
// Phase B (after relaxed grid barrier, co-residency guaranteed: LDS 16.5KB &
// VGPR<=170 via __launch_bounds__(256,3) -> capacity >= 3*256 = 768 blocks):
// one 64x128 QKV tile per block (768 = 64 x 12).
__global__ __launch_bounds__(256, 3) void prep_qkv_k(
    const float* __restrict__ nodes, const void* __restrict__ mask,
    const float* __restrict__ wq, const float* __restrict__ wkv,
    const float* __restrict__ wo,
    const float* __restrict__ bq, const float* __restrict__ bkv,
    unsigned short* __restrict__ XB, unsigned short* __restrict__ WQKVT,
    unsigned short* __restrict__ WOT, unsigned int* __restrict__ pm,
    unsigned short* __restrict__ Qo, unsigned short* __restrict__ Ko,
    unsigned short* __restrict__ VTo, unsigned int* __restrict__ gcnt) {
  __shared__ unsigned short smem[8192];      // 16 KB: prep t2 (8KB) / qkv sA+sB
  __shared__ int modeS;
  const int blk = blockIdx.x;
  const int tid = threadIdx.x;
  const int wave = tid >> 6, lane = tid & 63, quad = lane >> 4, l16 = lane & 15;

  // ---------------- phase A: prep (grid-stride 768) ----------------
  {
    unsigned short* t2 = smem;               // 8 KB
    for (int bid = blk; bid < 10624; bid += 768) {
      __syncthreads();                       // protect LDS reuse across units
      if (bid < 8192) {
        // ---- mask pack: thread handles 4 elems; 8 threads -> one 32-bit word ----
        const unsigned int* md = (const unsigned int*)mask;
        unsigned int probe = md[tid];
        bool odd = (probe > 1u && probe != 0x3f800000u);
        if (tid == 0) modeS = 0;
        __syncthreads();
        if (odd) atomicOr(&modeS, 1);
        __syncthreads();
        int byteMode = modeS;
        int t = bid * 256 + tid;
        unsigned int n;
        if (byteMode) {
          unsigned int x = md[t];
          n = ((x & 0xffu) ? 1u : 0u) | ((x & 0xff00u) ? 2u : 0u) |
              ((x & 0xff0000u) ? 4u : 0u) | ((x >> 24) ? 8u : 0u);
        } else {
          uint4 v = ((const uint4*)mask)[t];
          n = (v.x ? 1u : 0u) | (v.y ? 2u : 0u) | (v.z ? 4u : 0u) | (v.w ? 8u : 0u);
        }
        unsigned int w = n << ((lane & 7) * 4);
        w |= __shfl_xor(w, 1);
        w |= __shfl_xor(w, 2);
        w |= __shfl_xor(w, 4);
        if ((lane & 7) == 0) pm[t >> 3] = w;
      } else if (bid < 10240) {
        // ---- nodes fp32 -> bf16 ----
        int i = (bid - 8192) * 256 + tid;
        float4 v = ((const float4*)nodes)[i];
        us4v o;
        o[0] = f2bf(v.x); o[1] = f2bf(v.y); o[2] = f2bf(v.z); o[3] = f2bf(v.w);
        *(us4v*)(XB + (size_t)i * 4) = o;
      } else {
        // ---- weight transpose fp32 [512][C] -> bf16 dst[(c0+c)*512+k] ----
        int tb = bid - 10240;
        int x = tb & 15, y = (tb >> 4) & 7, z = tb >> 7;
        const float* src; unsigned short* dst; int C, c0;
        bool active = true;
        if (z == 0)      { if (x >= 8) active = false; src = wq;  dst = WQKVT; C = 512;  c0 = 0; }
        else if (z == 1) { src = wkv; dst = WQKVT; C = 1024; c0 = 512; }
        else             { if (x >= 8) active = false; src = wo;  dst = WOT;  C = 512;  c0 = 0; }
        if (active) {                        // block-uniform condition
          const int t = tid;
          const int ct = x * 64, rt = y * 64;
          for (int p = 0; p < 4; p++) {
            int kl = p * 16 + (t >> 4);
            int cc = (t & 15) * 4;
            float4 v = *(const float4*)&src[(size_t)(rt + kl) * C + ct + cc];
            float f[4] = {v.x, v.y, v.z, v.w};
            for (int i = 0; i < 4; i++) {
              int c = cc + i;
              t2[c * 64 + (kl ^ (c & 56))] = f2bf(f[i]);
            }
          }
          __syncthreads();
          for (int p = 0; p < 2; p++) {
            int c = p * 32 + (t >> 3);
            int kc = (t & 7) * 8;
            us8 v = *(const us8*)&t2[c * 64 + (kc ^ (c & 56))];
            *(us8*)&dst[(size_t)(c0 + ct + c) * 512 + rt + kc] = v;
          }
        }
      }
    }
  }
  grid_bar(gcnt, 768, tid);

  // ---------------- phase B: QKV GEMM, one 64x128 tile per block ----------------
  {
    unsigned short* sA = smem;
    unsigned short* sB = smem + 2048;
    const int wm = wave >> 1, wn = wave & 1;
    const int bm = blk & 63, bn = blk >> 6;
    floatx4 acc[2][4] = {};
    const int arow = lane >> 2;
    const int ag = lane & 3;
    for (int kt = 0; kt < 16; kt++) {
      __syncthreads();
      {
        int rowA = wave * 16 + arow;
        int gA = ag ^ (rowA & 3);
        gld16(&XB[(size_t)(bm * 64 + rowA) * 512 + kt * 32 + gA * 8], &sA[(wave * 16) * 32]);
        for (int p = 0; p < 2; p++) {
          int rowB = p * 64 + wave * 16 + arow;
          int gB = ag ^ (rowB & 3);
          gld16(&WQKVT[(size_t)(bn * 128 + rowB) * 512 + kt * 32 + gB * 8],
                &sB[(p * 64 + wave * 16) * 32]);
        }
      }
      __syncthreads();
      bf16x8 aF[2], bF[4];
      int swz = (quad ^ (l16 & 3)) * 8;
      for (int i = 0; i < 2; i++) aF[i] = ld8(&sA[(wm * 32 + i * 16 + l16) * 32 + swz]);
      for (int j = 0; j < 4; j++) bF[j] = ld8(&sB[(wn * 64 + j * 16 + l16) * 32 + swz]);
      for (int i = 0; i < 2; i++)
        for (int j = 0; j < 4; j++)
          acc[i][j] = __builtin_amdgcn_mfma_f32_16x16x32_bf16(aF[i], bF[j], acc[i][j], 0, 0, 0);
    }

    const int sec = bn * 2 + wn;             // 0..23: Q heads 0-7, K 8-15, V 16-23
    float bias[4];
    float scale = 1.0f;
    if (sec < 8) {
      for (int j = 0; j < 4; j++) bias[j] = bq[sec * 64 + j * 16 + l16];
      scale = 0.18033688011112042f;          // 0.125 * log2(e)
    } else {
      for (int j = 0; j < 4; j++) bias[j] = bkv[(sec - 8) * 64 + j * 16 + l16];
    }
    const int gr0 = bm * 64 + wm * 32;
    const int b = gr0 >> 11, n0 = gr0 & 2047;
    unsigned short* pw = smem + wave * 2048;
    __syncthreads();
    if (sec < 16) {
      for (int i = 0; i < 2; i++)
        for (int j = 0; j < 4; j++) {
          int cg2 = j * 2 + (l16 >> 3), ci = l16 & 7;
          for (int r = 0; r < 4; r++) {
            int row = i * 16 + quad * 4 + r;
            pw[row * 64 + ((cg2 ^ (row & 7)) * 8) + ci] = f2bf((acc[i][j][r] + bias[j]) * scale);
          }
        }
      WAIT_LGKM0();
      unsigned short* dst = (sec < 8) ? Qo + ((size_t)(b * 8 + sec) * 2048 + n0) * 64
                                      : Ko + ((size_t)(b * 8 + sec - 8) * 2048 + n0) * 64;
      for (int p = 0; p < 4; p++) {
        int row = p * 8 + (lane >> 3);
        int c8 = lane & 7;
        us8 v = *(const us8*)&pw[row * 64 + ((c8 ^ (row & 7)) * 8)];
        *(us8*)&dst[(size_t)row * 64 + c8 * 8] = v;
      }
    } else {
      // V: [64 d][32 n] s-permuted; local n = i*16 + quad*4 + r -> s = quad*8 + i*4 + r
      for (int i = 0; i < 2; i++)
        for (int j = 0; j < 4; j++) {
          int d = j * 16 + l16;
          us4v tv;
          for (int r = 0; r < 4; r++) tv[r] = f2bf(acc[i][j][r] + bias[j]);
          *(us4v*)&pw[d * 32 + ((quad ^ (d & 3)) * 8) + i * 4] = tv;
        }
      WAIT_LGKM0();
      unsigned short* dst = VTo + (size_t)(b * 8 + sec - 16) * 64 * 2048 + n0;
      for (int p = 0; p < 4; p++) {
        int d = p * 16 + (lane >> 2);
        int c4 = lane & 3;
        us8 v = *(const us8*)&pw[d * 32 + ((c4 ^ (d & 3)) * 8)];
        *(us8*)&dst[(size_t)d * 2048 + c4 * 8] = v;
      }
    }
  }
}

// ================= kernel 2: flash attention + last-arriver out GEMM =================
// Attn body verbatim R2 (verified). After writing its AO slice, each of the 8
// head-blocks of a (b,qt) group fences + bumps tcnt[b*32+qt]; the 8th arriver
// (zero spin, no co-residency needed) invalidates caches and computes the
// 64-token x 512 output GEMM for that row range, overlapped with other blocks.
__global__ __launch_bounds__(256, 2) void attn_out_k(
    const unsigned short* __restrict__ Q,    // [16][2048][64], pre-scaled
    const unsigned short* __restrict__ K,    // [16][2048][64]
    const unsigned short* __restrict__ Vt,   // [16][64][2048] s-permuted
    const unsigned int* __restrict__ pm,     // [2][2048][64]
    unsigned short* __restrict__ AO,         // [2][2048][512]
    const unsigned short* __restrict__ Bt,   // WOT [512][512]
    const float* __restrict__ bo, float* __restrict__ out,
    unsigned int* __restrict__ tcnt) {
  __shared__ unsigned short kv[2][4][4096];
  __shared__ float lsumB[4][64];             // 1 KB
  __shared__ int winS;
  const int tid = threadIdx.x;
  const int wave = tid >> 6, lane = tid & 63, quad = lane >> 4, l16 = lane & 15;
  const int bh = blockIdx.x, qt = blockIdx.y, b = bh >> 3, h = bh & 7;
  const int q0 = qt * 64;
  const unsigned short* Qb = Q + (size_t)bh * 2048 * 64;
  const unsigned short* Kb = K + (size_t)bh * 2048 * 64;
  const unsigned short* Vb = Vt + (size_t)bh * 64 * 2048;
  const unsigned int* pmB = pm + (size_t)b * 2048 * 64;

  bf16x8 qF[4][2];
#pragma unroll
  for (int qb = 0; qb < 4; qb++) {
    qF[qb][0] = ld8(&Qb[(size_t)(q0 + qb * 16 + l16) * 64 + quad * 8]);
    qF[qb][1] = ld8(&Qb[(size_t)(q0 + qb * 16 + l16) * 64 + 32 + quad * 8]);
  }

  floatx4 oacc[4][4] = {};                   // [db][qb]
  floatx4 lsacc[4] = {};                     // ones-MFMA row sums, [qb]

  union { us8 u; bf16x8 v; } onesU;
#pragma unroll
  for (int i = 0; i < 8; i++) onesU.u[i] = 0x3f80;   // bf16 1.0
  const bf16x8 onesF = onesU.v;

  const int srow = lane >> 3;                // K staging: row-in-8
  const int gK = (lane & 7) ^ srow;          // K source d-group (3-bit XOR)
  const int dV = lane >> 2;                  // V staging: d-row-in-16
  const int gV = (lane & 3) ^ (dV & 3);      // V source s-group (2-bit XOR)
  const int rsw0 = quad ^ (l16 & 7);
  const int rsw1 = (4 + quad) ^ (l16 & 7);

  unsigned short* kv0 = &kv[0][wave][0];
  unsigned short* kv1 = &kv[1][wave][0];

  struct MW { unsigned int w[4]; };
  MW mwA, mwB;

  auto prefetch = [&](int it, unsigned short* dst, MW& mw) {
    const int k0w = it * 128 + wave * 32;
#pragma unroll
    for (int qb = 0; qb < 4; qb++)
      mw.w[qb] = pmB[(size_t)(q0 + qb * 16 + l16) * 64 + it * 4 + wave];
#pragma unroll
    for (int p = 0; p < 4; p++) {
      gld16(&Kb[(size_t)(k0w + p * 8 + srow) * 64 + gK * 8], dst + p * 512);
      gld16(&Vb[(size_t)(p * 16 + dV) * 2048 + k0w + gV * 8], dst + 2048 + p * 512);
    }
  };

  auto step = [&](const unsigned short* buf, const MW& mw) {
    floatx4 st[4][2];
    __builtin_amdgcn_s_setprio(1);
#pragma unroll
    for (int k2 = 0; k2 < 2; k2++) {
      const unsigned short* kr = &buf[(k2 * 16 + l16) * 64];
      bf16x8 kf0 = ld8(kr + rsw0 * 8);
      bf16x8 kf1 = ld8(kr + rsw1 * 8);
#pragma unroll
      for (int qb = 0; qb < 4; qb++) {
        floatx4 z = {0.f, 0.f, 0.f, 0.f};
        z = __builtin_amdgcn_mfma_f32_16x16x32_bf16(kf0, qF[qb][0], z, 0, 0, 0);
        st[qb][k2] = __builtin_amdgcn_mfma_f32_16x16x32_bf16(kf1, qF[qb][1], z, 0, 0, 0);
      }
    }
    __builtin_amdgcn_s_setprio(0);
    union uB { bf16x8 v; unsigned short u[8]; } pf[4];
#pragma unroll
    for (int qb = 0; qb < 4; qb++) {
      unsigned int w = mw.w[qb];
#pragma unroll
      for (int k2 = 0; k2 < 2; k2++) {
#pragma unroll
        for (int r = 0; r < 4; r++) {
          float e = exp2c(st[qb][k2][r]);
          e = ((w >> (k2 * 16 + quad * 4 + r)) & 1u) ? e : 0.f;
          pf[qb].u[k2 * 4 + r] = f2bf(e);
        }
      }
    }
    __builtin_amdgcn_s_setprio(1);
#pragma unroll
    for (int qb = 0; qb < 4; qb++)
      lsacc[qb] = __builtin_amdgcn_mfma_f32_16x16x32_bf16(onesF, pf[qb].v, lsacc[qb], 0, 0, 0);
#pragma unroll
    for (int db = 0; db < 4; db++) {
      const int d = db * 16 + l16;
      bf16x8 va = ld8(&buf[2048 + d * 32 + ((quad ^ (d & 3)) * 8)]);
#pragma unroll
      for (int qb = 0; qb < 4; qb++)
        oacc[db][qb] =
            __builtin_amdgcn_mfma_f32_16x16x32_bf16(va, pf[qb].v, oacc[db][qb], 0, 0, 0);
    }
    __builtin_amdgcn_s_setprio(0);
  };

  SB();
  prefetch(0, kv0, mwA);
  SB();
#pragma unroll 1
  for (int i = 0; i < 8; ++i) {
    prefetch(i * 2 + 1, kv1, mwB);
    SB();
    WAIT_VM12();
    SB();
    step(kv0, mwA);
    SB();
    if (i < 7) {
      prefetch(i * 2 + 2, kv0, mwA);
      SB();
      WAIT_VM12();
      SB();
    } else {
      WAIT_VM0();
      SB();
    }
    step(kv1, mwB);
    SB();
  }

  if (quad == 0) {
#pragma unroll
    for (int qb = 0; qb < 4; qb++) lsumB[wave][qb * 16 + l16] = lsacc[qb][0];
  }
  __syncthreads();                           // all waves done with kv buffers

  float* pO = (float*)&kv[0][0][0];          // 64 KB = 4 regions x 16 KB
  float* myR = pO + wave * 4096;
#pragma unroll
  for (int db = 0; db < 4; db++)
#pragma unroll
    for (int qb = 0; qb < 4; qb++) {
      int q = qb * 16 + l16;
      *(floatx4*)&myR[q * 64 + (((db * 4 + quad) ^ l16) & 15) * 4] = oacc[db][qb];
    }
  __syncthreads();
  {
    int q = tid >> 2, dblk = tid & 3;
    float inv = 1.0f / (lsumB[0][q] + lsumB[1][q] + lsumB[2][q] + lsumB[3][q]);
    float o[16];
    for (int i = 0; i < 4; i++) {
      int dg = dblk * 4 + i;
      int off = q * 64 + ((dg ^ q) & 15) * 4;
      floatx4 s = *(floatx4*)&pO[off];
      s += *(floatx4*)&pO[4096 + off];
      s += *(floatx4*)&pO[8192 + off];
      s += *(floatx4*)&pO[12288 + off];
      for (int r = 0; r < 4; r++) o[i * 4 + r] = s[r] * inv;
    }
    us8 v0, v1;
    for (int i = 0; i < 8; i++) { v0[i] = f2bf(o[i]); v1[i] = f2bf(o[8 + i]); }
    unsigned short* dst = &AO[((size_t)b * 2048 + q0 + q) * 512 + h * 64 + dblk * 16];
    *(us8*)dst = v0;
    *(us8*)(dst + 8) = v1;
  }

  // ---- last-arriver out GEMM for this (b,qt) token tile ----
  __threadfence();                           // per-wave: drain own AO stores + wbl2
  __syncthreads();                           // all waves fenced
  if (tid == 0) {
    unsigned int old = __hip_atomic_fetch_add(&tcnt[b * 32 + qt], 1u,
                                              __ATOMIC_RELAXED, __HIP_MEMORY_SCOPE_AGENT);
    winS = (old == 7u);
  }
  __syncthreads();
  if (!winS) return;
  __threadfence();                           // acquire: invalidate stale L1/L2

  {
    unsigned short* sA = &kv[0][0][0];       // reuse 12 KB of kv LDS
    unsigned short* sB = sA + 2048;
    const int wm = wave >> 1, wn = wave & 1;
    const int bmrow = (b * 32 + qt) * 64;    // = b*2048 + qt*64
    const int arow = lane >> 2;
    const int ag = lane & 3;
    for (int bn = 0; bn < 4; bn++) {
      floatx4 acc[2][4] = {};
      for (int kt = 0; kt < 16; kt++) {
        __syncthreads();
        {
          int rowA = wave * 16 + arow;
          int gA = ag ^ (rowA & 3);
          gld16(&AO[(size_t)(bmrow + rowA) * 512 + kt * 32 + gA * 8], &sA[(wave * 16) * 32]);
          for (int p = 0; p < 2; p++) {
            int rowB = p * 64 + wave * 16 + arow;
            int gB = ag ^ (rowB & 3);
            gld16(&Bt[(size_t)(bn * 128 + rowB) * 512 + kt * 32 + gB * 8],
                  &sB[(p * 64 + wave * 16) * 32]);
          }
        }
        __syncthreads();
        bf16x8 aF[2], bF[4];
        int swz = (quad ^ (l16 & 3)) * 8;
        for (int i = 0; i < 2; i++) aF[i] = ld8(&sA[(wm * 32 + i * 16 + l16) * 32 + swz]);
        for (int j = 0; j < 4; j++) bF[j] = ld8(&sB[(wn * 64 + j * 16 + l16) * 32 + swz]);
        for (int i = 0; i < 2; i++)
          for (int j = 0; j < 4; j++)
            acc[i][j] = __builtin_amdgcn_mfma_f32_16x16x32_bf16(aF[i], bF[j], acc[i][j], 0, 0, 0);
      }
      for (int i = 0; i < 2; i++)
        for (int j = 0; j < 4; j++) {
          int gc = bn * 128 + wn * 64 + j * 16 + l16;
          float bb = bo[gc];
          for (int r = 0; r < 4; r++) {
            int gr = bmrow + wm * 32 + i * 16 + quad * 4 + r;
            out[(size_t)gr * 512 + gc] = acc[i][j][r] + bb;
          }
        }
    }
  }
}

// ---------------- launch ----------------
extern "C" void kernel_launch(void* const* d_in, const int* in_sizes, int n_in,
                              void* d_out, int out_size, void* d_ws, size_t ws_size,
                              hipStream_t stream) {
  const float* nodes = (const float*)d_in[0];
  const void*  mask  = d_in[1];
  const float* wq    = (const float*)d_in[2];
  const float* bq    = (const float*)d_in[3];
  const float* wkv   = (const float*)d_in[4];
  const float* bkv   = (const float*)d_in[5];
  const float* wo    = (const float*)d_in[6];
  const float* bo    = (const float*)d_in[7];
  float* out = (float*)d_out;

  char* ws = (char*)d_ws;
  unsigned short* XB    = (unsigned short*)(ws + 0);          //  4 MB  bf16 nodes
  unsigned short* WQKVT = (unsigned short*)(ws + 4194304);    //  1.5MB
  unsigned short* WOT   = (unsigned short*)(ws + 5767168);    //  0.5MB
  unsigned short* Qm    = (unsigned short*)(ws + 6291456);    //  4 MB  [16][2048][64]
  unsigned short* Km    = (unsigned short*)(ws + 10485760);   //  4 MB
  unsigned short* VTm   = (unsigned short*)(ws + 18874368);   //  4 MB  [16][64][2048] s-perm
  unsigned short* AOm   = (unsigned short*)(ws + 23068672);   //  4 MB  [4096][512]
  unsigned int*   PM    = (unsigned int*)(ws + 27262976);     //  1 MB  packed mask
  unsigned int*   CNT   = (unsigned int*)(ws + 28311552);     //  [0]=barrier, [16..79]=tile cnts

  hipMemsetAsync(CNT, 0, 512, stream);
  prep_qkv_k<<<768, 256, 0, stream>>>(nodes, mask, wq, wkv, wo, bq, bkv,
                                      XB, WQKVT, WOT, PM, Qm, Km, VTm, CNT);
  attn_out_k<<<dim3(16, 32), 256, 0, stream>>>(Qm, Km, VTm, PM, AOm,
                                               WOT, bo, out, CNT + 16);
}

// Round 8
// 170.798 us; speedup vs baseline: 2.0299x; 2.0299x over previous
//
#include <hip/hip_runtime.h>
#include <cstdint>
#include <cstddef>

#define DEVI __device__ __forceinline__

typedef __bf16 bf16x8 __attribute__((ext_vector_type(8)));
typedef float floatx4 __attribute__((ext_vector_type(4)));
typedef unsigned short us4v __attribute__((ext_vector_type(4)));
typedef unsigned short us8 __attribute__((ext_vector_type(8)));

static_assert(sizeof(bf16x8) == 16, "bf16x8 must be 16B");
static_assert(sizeof(us8) == 16, "us8 must be 16B");

// ---------------- helpers ----------------

#if __has_builtin(__builtin_amdgcn_cvt_pk_bf16_f32)
DEVI unsigned short f2bf(float f) {
  typedef __bf16 bf16x2 __attribute__((ext_vector_type(2)));
  union { bf16x2 v; unsigned short u[2]; } c;
  c.v = __builtin_amdgcn_cvt_pk_bf16_f32(f, 0.f);
  return c.u[0];
}
#else
DEVI unsigned short f2bf(float f) {
  unsigned int u = __float_as_uint(f);
  u += 0x7fffu + ((u >> 16) & 1u);   // RNE
  return (unsigned short)(u >> 16);
}
#endif

DEVI float exp2c(float x) {
#if __has_builtin(__builtin_amdgcn_exp2f)
  return __builtin_amdgcn_exp2f(x);
#else
  return exp2f(x);
#endif
}

DEVI bf16x8 ld8(const unsigned short* p) { return *(const bf16x8*)p; }

typedef const __attribute__((address_space(1))) void* gas_ptr;
typedef __attribute__((address_space(3))) void* las_ptr;

DEVI void gld16(const void* g, void* l) {
  __builtin_amdgcn_global_load_lds((gas_ptr)g, (las_ptr)l, 16, 0, 0);
}

#define WAIT_LGKM0() __builtin_amdgcn_s_waitcnt(0xc07f)   // lgkmcnt(0) only
#define WAIT_VM12()  __builtin_amdgcn_s_waitcnt(0x0f7c)   // vmcnt(12) only
#define WAIT_VM0()   __builtin_amdgcn_s_waitcnt(0x0f70)   // vmcnt(0) only
#define SB()         __builtin_amdgcn_sched_barrier(0)

// sc1-coherent 8B accesses (bypass non-coherent per-XCD L2; NO bulk fences)
DEVI void st8_sc1(unsigned long long* p, unsigned long long v) {
  __hip_atomic_store(p, v, __ATOMIC_RELAXED, __HIP_MEMORY_SCOPE_AGENT);
}
DEVI unsigned long long ld8_sc1(const unsigned long long* p) {
  return __hip_atomic_load(p, __ATOMIC_RELAXED, __HIP_MEMORY_SCOPE_AGENT);
}

// ---------------- fused prep: mask bitpack + nodes cvt + weight transposes ----------------
// flat grid: [0,8192) pack, [8192,10240) cvt, [10240,10624) transposes (16x8x3)
__global__ __launch_bounds__(256) void prep_k(
    const float* __restrict__ nodes, const void* __restrict__ mask,
    const float* __restrict__ wq, const float* __restrict__ wkv,
    const float* __restrict__ wo,
    unsigned short* __restrict__ XB, unsigned short* __restrict__ WQKVT,
    unsigned short* __restrict__ WOT, unsigned int* __restrict__ pm) {
  int bid = blockIdx.x;
  if (bid < 8192) {
    // ---- mask pack: thread handles 4 elems; 8 threads -> one 32-bit word ----
    __shared__ int mode;
    const unsigned int* md = (const unsigned int*)mask;
    unsigned int probe = md[threadIdx.x];
    bool odd = (probe > 1u && probe != 0x3f800000u);
    if (threadIdx.x == 0) mode = 0;
    __syncthreads();
    if (odd) atomicOr(&mode, 1);
    __syncthreads();
    int byteMode = mode;
    int t = bid * 256 + threadIdx.x;
    int lane = threadIdx.x & 63;
    unsigned int n;
    if (byteMode) {
      unsigned int x = md[t];
      n = ((x & 0xffu) ? 1u : 0u) | ((x & 0xff00u) ? 2u : 0u) |
          ((x & 0xff0000u) ? 4u : 0u) | ((x >> 24) ? 8u : 0u);
    } else {
      uint4 v = ((const uint4*)mask)[t];
      n = (v.x ? 1u : 0u) | (v.y ? 2u : 0u) | (v.z ? 4u : 0u) | (v.w ? 8u : 0u);
    }
    unsigned int w = n << ((lane & 7) * 4);
    w |= __shfl_xor(w, 1);
    w |= __shfl_xor(w, 2);
    w |= __shfl_xor(w, 4);
    if ((lane & 7) == 0) pm[t >> 3] = w;
  } else if (bid < 10240) {
    // ---- nodes fp32 -> bf16 ----
    int i = (bid - 8192) * 256 + threadIdx.x;
    float4 v = ((const float4*)nodes)[i];
    us4v o;
    o[0] = f2bf(v.x); o[1] = f2bf(v.y); o[2] = f2bf(v.z); o[3] = f2bf(v.w);
    *(us4v*)(XB + (size_t)i * 4) = o;
  } else {
    // ---- weight transpose fp32 [512][C] -> bf16 dst[(c0+c)*512+k] ----
    int tb = bid - 10240;
    int x = tb & 15, y = (tb >> 4) & 7, z = tb >> 7;
    const float* src; unsigned short* dst; int C, c0;
    if (z == 0)      { if (x >= 8) return; src = wq;  dst = WQKVT; C = 512;  c0 = 0; }
    else if (z == 1) { src = wkv; dst = WQKVT; C = 1024; c0 = 512; }
    else             { if (x >= 8) return; src = wo;  dst = WOT;  C = 512;  c0 = 0; }
    __shared__ unsigned short t2[64 * 64];
    const int t = threadIdx.x;
    const int ct = x * 64, rt = y * 64;
    for (int p = 0; p < 4; p++) {
      int kl = p * 16 + (t >> 4);
      int cc = (t & 15) * 4;
      float4 v = *(const float4*)&src[(size_t)(rt + kl) * C + ct + cc];
      float f[4] = {v.x, v.y, v.z, v.w};
      for (int i = 0; i < 4; i++) {
        int c = cc + i;
        t2[c * 64 + (kl ^ (c & 56))] = f2bf(f[i]);
      }
    }
    __syncthreads();
    for (int p = 0; p < 2; p++) {
      int c = p * 32 + (t >> 3);
      int kc = (t & 7) * 8;
      us8 v = *(const us8*)&t2[c * 64 + (kc ^ (c & 56))];
      *(us8*)&dst[(size_t)(c0 + ct + c) * 512 + rt + kc] = v;
    }
  }
}

// ---------------- QKV GEMM: 64x128 tiles, grid (64,12) ----------------
__global__ __launch_bounds__(256) void gemm_qkv_k(
    const unsigned short* __restrict__ A,    // [4096][512]
    const unsigned short* __restrict__ Bt,   // [1536][512]
    const float* __restrict__ bq, const float* __restrict__ bkv,
    unsigned short* __restrict__ Qo, unsigned short* __restrict__ Ko,
    unsigned short* __restrict__ VTo) {
  __shared__ unsigned short smem[8192];
  unsigned short* sA = smem;
  unsigned short* sB = smem + 2048;
  const int tid = threadIdx.x;
  const int wave = tid >> 6, lane = tid & 63, quad = lane >> 4, l16 = lane & 15;
  const int wm = wave >> 1, wn = wave & 1;
  const int bm = blockIdx.x, bn = blockIdx.y;
  floatx4 acc[2][4] = {};
  const int arow = lane >> 2;
  const int ag = lane & 3;
  for (int kt = 0; kt < 16; kt++) {
    __syncthreads();
    {
      int rowA = wave * 16 + arow;
      int gA = ag ^ (rowA & 3);
      gld16(&A[(size_t)(bm * 64 + rowA) * 512 + kt * 32 + gA * 8], &sA[(wave * 16) * 32]);
      for (int p = 0; p < 2; p++) {
        int rowB = p * 64 + wave * 16 + arow;
        int gB = ag ^ (rowB & 3);
        gld16(&Bt[(size_t)(bn * 128 + rowB) * 512 + kt * 32 + gB * 8],
              &sB[(p * 64 + wave * 16) * 32]);
      }
    }
    __syncthreads();
    bf16x8 aF[2], bF[4];
    int swz = (quad ^ (l16 & 3)) * 8;
    for (int i = 0; i < 2; i++) aF[i] = ld8(&sA[(wm * 32 + i * 16 + l16) * 32 + swz]);
    for (int j = 0; j < 4; j++) bF[j] = ld8(&sB[(wn * 64 + j * 16 + l16) * 32 + swz]);
    for (int i = 0; i < 2; i++)
      for (int j = 0; j < 4; j++)
        acc[i][j] = __builtin_amdgcn_mfma_f32_16x16x32_bf16(aF[i], bF[j], acc[i][j], 0, 0, 0);
  }

  const int sec = bn * 2 + wn;               // 0..23: Q heads 0-7, K 8-15, V 16-23
  float bias[4];
  float scale = 1.0f;
  if (sec < 8) {
    for (int j = 0; j < 4; j++) bias[j] = bq[sec * 64 + j * 16 + l16];
    scale = 0.18033688011112042f;            // 0.125 * log2(e)
  } else {
    for (int j = 0; j < 4; j++) bias[j] = bkv[(sec - 8) * 64 + j * 16 + l16];
  }
  const int gr0 = bm * 64 + wm * 32;
  const int b = gr0 >> 11, n0 = gr0 & 2047;
  unsigned short* pw = smem + wave * 2048;
  __syncthreads();
  if (sec < 16) {
    for (int i = 0; i < 2; i++)
      for (int j = 0; j < 4; j++) {
        int cg = j * 2 + (l16 >> 3), ci = l16 & 7;
        for (int r = 0; r < 4; r++) {
          int row = i * 16 + quad * 4 + r;
          pw[row * 64 + ((cg ^ (row & 7)) * 8) + ci] = f2bf((acc[i][j][r] + bias[j]) * scale);
        }
      }
    WAIT_LGKM0();
    unsigned short* dst = (sec < 8) ? Qo + ((size_t)(b * 8 + sec) * 2048 + n0) * 64
                                    : Ko + ((size_t)(b * 8 + sec - 8) * 2048 + n0) * 64;
    for (int p = 0; p < 4; p++) {
      int row = p * 8 + (lane >> 3);
      int c8 = lane & 7;
      us8 v = *(const us8*)&pw[row * 64 + ((c8 ^ (row & 7)) * 8)];
      *(us8*)&dst[(size_t)row * 64 + c8 * 8] = v;
    }
  } else {
    // V: [64 d][32 n] s-permuted; local n = i*16 + quad*4 + r -> s = quad*8 + i*4 + r
    for (int i = 0; i < 2; i++)
      for (int j = 0; j < 4; j++) {
        int d = j * 16 + l16;
        us4v t;
        for (int r = 0; r < 4; r++) t[r] = f2bf(acc[i][j][r] + bias[j]);
        *(us4v*)&pw[d * 32 + ((quad ^ (d & 3)) * 8) + i * 4] = t;
      }
    WAIT_LGKM0();
    unsigned short* dst = VTo + (size_t)(b * 8 + sec - 16) * 64 * 2048 + n0;
    for (int p = 0; p < 4; p++) {
      int d = p * 16 + (lane >> 2);
      int c4 = lane & 3;
      us8 v = *(const us8*)&pw[d * 32 + ((c4 ^ (d & 3)) * 8)];
      *(us8*)&dst[(size_t)d * 2048 + c4 * 8] = v;
    }
  }
}

// ================= flash attention + fence-free 8-way last-arriver out GEMM =================
// Attn body verbatim R2 (verified). AO written via sc1 atomic stores (device-
// coherent, no wbl2/inv). Each (b,qt) group's 8 blocks bump a counter, relaxed-
// poll to 8 (R6-proven cheap), then EACH computes its head's 64x64 out chunk.
// Co-residency: 512 blocks at exactly 2/CU (67KB LDS) -- R7-validated.
__global__ __launch_bounds__(256, 2) void attn_out_k(
    const unsigned short* __restrict__ Q,    // [16][2048][64], pre-scaled
    const unsigned short* __restrict__ K,    // [16][2048][64]
    const unsigned short* __restrict__ Vt,   // [16][64][2048] s-permuted
    const unsigned int* __restrict__ pm,     // [2][2048][64]
    unsigned short* __restrict__ AO,         // [2][2048][512]
    const unsigned short* __restrict__ Bt,   // WOT [512][512]
    const float* __restrict__ bo, float* __restrict__ out,
    unsigned int* __restrict__ tcnt) {
  __shared__ unsigned short kv[2][4][4096];
  __shared__ float lsumB[4][64];             // 1 KB
  const int tid = threadIdx.x;
  const int wave = tid >> 6, lane = tid & 63, quad = lane >> 4, l16 = lane & 15;
  const int bh = blockIdx.x, qt = blockIdx.y, b = bh >> 3, h = bh & 7;
  const int q0 = qt * 64;
  const unsigned short* Qb = Q + (size_t)bh * 2048 * 64;
  const unsigned short* Kb = K + (size_t)bh * 2048 * 64;
  const unsigned short* Vb = Vt + (size_t)bh * 64 * 2048;
  const unsigned int* pmB = pm + (size_t)b * 2048 * 64;

  bf16x8 qF[4][2];
#pragma unroll
  for (int qb = 0; qb < 4; qb++) {
    qF[qb][0] = ld8(&Qb[(size_t)(q0 + qb * 16 + l16) * 64 + quad * 8]);
    qF[qb][1] = ld8(&Qb[(size_t)(q0 + qb * 16 + l16) * 64 + 32 + quad * 8]);
  }

  floatx4 oacc[4][4] = {};                   // [db][qb]
  floatx4 lsacc[4] = {};                     // ones-MFMA row sums, [qb]

  union { us8 u; bf16x8 v; } onesU;
#pragma unroll
  for (int i = 0; i < 8; i++) onesU.u[i] = 0x3f80;   // bf16 1.0
  const bf16x8 onesF = onesU.v;

  const int srow = lane >> 3;                // K staging: row-in-8
  const int gK = (lane & 7) ^ srow;          // K source d-group (3-bit XOR)
  const int dV = lane >> 2;                  // V staging: d-row-in-16
  const int gV = (lane & 3) ^ (dV & 3);      // V source s-group (2-bit XOR)
  const int rsw0 = quad ^ (l16 & 7);
  const int rsw1 = (4 + quad) ^ (l16 & 7);

  unsigned short* kv0 = &kv[0][wave][0];
  unsigned short* kv1 = &kv[1][wave][0];

  struct MW { unsigned int w[4]; };
  MW mwA, mwB;

  auto prefetch = [&](int it, unsigned short* dst, MW& mw) {
    const int k0w = it * 128 + wave * 32;
#pragma unroll
    for (int qb = 0; qb < 4; qb++)
      mw.w[qb] = pmB[(size_t)(q0 + qb * 16 + l16) * 64 + it * 4 + wave];
#pragma unroll
    for (int p = 0; p < 4; p++) {
      gld16(&Kb[(size_t)(k0w + p * 8 + srow) * 64 + gK * 8], dst + p * 512);
      gld16(&Vb[(size_t)(p * 16 + dV) * 2048 + k0w + gV * 8], dst + 2048 + p * 512);
    }
  };

  auto step = [&](const unsigned short* buf, const MW& mw) {
    floatx4 st[4][2];
    __builtin_amdgcn_s_setprio(1);
#pragma unroll
    for (int k2 = 0; k2 < 2; k2++) {
      const unsigned short* kr = &buf[(k2 * 16 + l16) * 64];
      bf16x8 kf0 = ld8(kr + rsw0 * 8);
      bf16x8 kf1 = ld8(kr + rsw1 * 8);
#pragma unroll
      for (int qb = 0; qb < 4; qb++) {
        floatx4 z = {0.f, 0.f, 0.f, 0.f};
        z = __builtin_amdgcn_mfma_f32_16x16x32_bf16(kf0, qF[qb][0], z, 0, 0, 0);
        st[qb][k2] = __builtin_amdgcn_mfma_f32_16x16x32_bf16(kf1, qF[qb][1], z, 0, 0, 0);
      }
    }
    __builtin_amdgcn_s_setprio(0);
    union uB { bf16x8 v; unsigned short u[8]; } pf[4];
#pragma unroll
    for (int qb = 0; qb < 4; qb++) {
      unsigned int w = mw.w[qb];
#pragma unroll
      for (int k2 = 0; k2 < 2; k2++) {
#pragma unroll
        for (int r = 0; r < 4; r++) {
          float e = exp2c(st[qb][k2][r]);
          e = ((w >> (k2 * 16 + quad * 4 + r)) & 1u) ? e : 0.f;
          pf[qb].u[k2 * 4 + r] = f2bf(e);
        }
      }
    }
    __builtin_amdgcn_s_setprio(1);
#pragma unroll
    for (int qb = 0; qb < 4; qb++)
      lsacc[qb] = __builtin_amdgcn_mfma_f32_16x16x32_bf16(onesF, pf[qb].v, lsacc[qb], 0, 0, 0);
#pragma unroll
    for (int db = 0; db < 4; db++) {
      const int d = db * 16 + l16;
      bf16x8 va = ld8(&buf[2048 + d * 32 + ((quad ^ (d & 3)) * 8)]);
#pragma unroll
      for (int qb = 0; qb < 4; qb++)
        oacc[db][qb] =
            __builtin_amdgcn_mfma_f32_16x16x32_bf16(va, pf[qb].v, oacc[db][qb], 0, 0, 0);
    }
    __builtin_amdgcn_s_setprio(0);
  };

  SB();
  prefetch(0, kv0, mwA);
  SB();
#pragma unroll 1
  for (int i = 0; i < 8; ++i) {
    prefetch(i * 2 + 1, kv1, mwB);
    SB();
    WAIT_VM12();
    SB();
    step(kv0, mwA);
    SB();
    if (i < 7) {
      prefetch(i * 2 + 2, kv0, mwA);
      SB();
      WAIT_VM12();
      SB();
    } else {
      WAIT_VM0();
      SB();
    }
    step(kv1, mwB);
    SB();
  }

  if (quad == 0) {
#pragma unroll
    for (int qb = 0; qb < 4; qb++) lsumB[wave][qb * 16 + l16] = lsacc[qb][0];
  }
  __syncthreads();                           // all waves done with kv buffers

  float* pO = (float*)&kv[0][0][0];          // 64 KB = 4 regions x 16 KB
  float* myR = pO + wave * 4096;
#pragma unroll
  for (int db = 0; db < 4; db++)
#pragma unroll
    for (int qb = 0; qb < 4; qb++) {
      int q = qb * 16 + l16;
      *(floatx4*)&myR[q * 64 + (((db * 4 + quad) ^ l16) & 15) * 4] = oacc[db][qb];
    }
  __syncthreads();
  {
    int q = tid >> 2, dblk = tid & 3;
    float inv = 1.0f / (lsumB[0][q] + lsumB[1][q] + lsumB[2][q] + lsumB[3][q]);
    float o[16];
    for (int i = 0; i < 4; i++) {
      int dg = dblk * 4 + i;
      int off = q * 64 + ((dg ^ q) & 15) * 4;
      floatx4 s = *(floatx4*)&pO[off];
      s += *(floatx4*)&pO[4096 + off];
      s += *(floatx4*)&pO[8192 + off];
      s += *(floatx4*)&pO[12288 + off];
      for (int r = 0; r < 4; r++) o[i * 4 + r] = s[r] * inv;
    }
    union { us8 v; unsigned long long q2[2]; } v0, v1;
    for (int i = 0; i < 8; i++) { v0.v[i] = f2bf(o[i]); v1.v[i] = f2bf(o[8 + i]); }
    // sc1 stores: device-coherent, bypass non-coherent L2, no fences needed
    unsigned long long* dst =
        (unsigned long long*)&AO[((size_t)b * 2048 + q0 + q) * 512 + h * 64 + dblk * 16];
    st8_sc1(dst + 0, v0.q2[0]);
    st8_sc1(dst + 1, v0.q2[1]);
    st8_sc1(dst + 2, v1.q2[0]);
    st8_sc1(dst + 3, v1.q2[1]);
  }

  // ---- group rendezvous: bump + relaxed poll to 8 (NO fences) ----
  WAIT_VM0();                                // own sc1 stores complete (at coherence point)
  __syncthreads();                           // all waves' stores drained
  if (tid == 0) {
    __hip_atomic_fetch_add(&tcnt[b * 32 + qt], 1u,
                           __ATOMIC_RELAXED, __HIP_MEMORY_SCOPE_AGENT);
    while (__hip_atomic_load(&tcnt[b * 32 + qt],
                             __ATOMIC_RELAXED, __HIP_MEMORY_SCOPE_AGENT) < 8u)
      __builtin_amdgcn_s_sleep(16);
  }
  __syncthreads();                           // whole block: all 8 AO slices visible

  // ---- out chunk: this head's 64 tokens x 64 cols of the final output ----
  {
    unsigned short* sA = &kv[0][0][0];       // 4 KB  [64 tok][32 k]
    unsigned short* sB = sA + 2048;          // 4 KB  [64 col][32 k]
    const int wm = wave >> 1, wn = wave & 1;
    const int bmrow = b * 2048 + qt * 64;
    const int arow = tid >> 2;               // 0..63
    const int ag4 = tid & 3;
    const int gA = ag4 ^ (arow & 3);
    const int browB = wave * 16 + (lane >> 2);
    const int gB = (lane & 3) ^ (browB & 3);
    floatx4 acc[2][2] = {};
    for (int kt = 0; kt < 16; kt++) {
      __syncthreads();
      {
        // A: AO rows via sc1 loads -> LDS (same XOR family as gemm staging)
        const unsigned long long* src = (const unsigned long long*)
            &AO[(size_t)(bmrow + arow) * 512 + kt * 32 + gA * 8];
        unsigned long long x0 = ld8_sc1(src);
        unsigned long long x1 = ld8_sc1(src + 1);
        unsigned long long* d = (unsigned long long*)&sA[arow * 32 + ag4 * 8];
        d[0] = x0; d[1] = x1;
        // B: WOT rows (pre-dispatch data, plain gld16)
        gld16(&Bt[(size_t)(h * 64 + browB) * 512 + kt * 32 + gB * 8],
              &sB[(wave * 16) * 32]);
      }
      __syncthreads();
      bf16x8 aF[2], bF[2];
      int swz = (quad ^ (l16 & 3)) * 8;
      for (int i = 0; i < 2; i++) aF[i] = ld8(&sA[(wm * 32 + i * 16 + l16) * 32 + swz]);
      for (int j = 0; j < 2; j++) bF[j] = ld8(&sB[(wn * 32 + j * 16 + l16) * 32 + swz]);
      for (int i = 0; i < 2; i++)
        for (int j = 0; j < 2; j++)
          acc[i][j] = __builtin_amdgcn_mfma_f32_16x16x32_bf16(aF[i], bF[j], acc[i][j], 0, 0, 0);
    }
    for (int i = 0; i < 2; i++)
      for (int j = 0; j < 2; j++) {
        int gc = h * 64 + wn * 32 + j * 16 + l16;
        float bb = bo[gc];
        for (int r = 0; r < 4; r++) {
          int gr = bmrow + wm * 32 + i * 16 + quad * 4 + r;
          out[(size_t)gr * 512 + gc] = acc[i][j][r] + bb;
        }
      }
  }
}

// ---------------- launch ----------------
extern "C" void kernel_launch(void* const* d_in, const int* in_sizes, int n_in,
                              void* d_out, int out_size, void* d_ws, size_t ws_size,
                              hipStream_t stream) {
  const float* nodes = (const float*)d_in[0];
  const void*  mask  = d_in[1];
  const float* wq    = (const float*)d_in[2];
  const float* bq    = (const float*)d_in[3];
  const float* wkv   = (const float*)d_in[4];
  const float* bkv   = (const float*)d_in[5];
  const float* wo    = (const float*)d_in[6];
  const float* bo    = (const float*)d_in[7];
  float* out = (float*)d_out;

  char* ws = (char*)d_ws;
  unsigned short* XB    = (unsigned short*)(ws + 0);          //  4 MB  bf16 nodes
  unsigned short* WQKVT = (unsigned short*)(ws + 4194304);    //  1.5MB
  unsigned short* WOT   = (unsigned short*)(ws + 5767168);    //  0.5MB
  unsigned short* Qm    = (unsigned short*)(ws + 6291456);    //  4 MB  [16][2048][64]
  unsigned short* Km    = (unsigned short*)(ws + 10485760);   //  4 MB
  unsigned short* VTm   = (unsigned short*)(ws + 18874368);   //  4 MB  [16][64][2048] s-perm
  unsigned short* AOm   = (unsigned short*)(ws + 23068672);   //  4 MB  [4096][512]
  unsigned int*   PM    = (unsigned int*)(ws + 27262976);     //  1 MB  packed mask
  unsigned int*   CNT   = (unsigned int*)(ws + 28311552);     //  tile counters

  hipMemsetAsync(CNT, 0, 512, stream);
  prep_k<<<10624, 256, 0, stream>>>(nodes, mask, wq, wkv, wo, XB, WQKVT, WOT, PM);
  gemm_qkv_k<<<dim3(64, 12), 256, 0, stream>>>(XB, WQKVT, bq, bkv, Qm, Km, VTm);
  attn_out_k<<<dim3(16, 32), 256, 0, stream>>>(Qm, Km, VTm, PM, AOm, WOT, bo, out, CNT);
}

// Round 10
// 167.461 us; speedup vs baseline: 2.0703x; 1.0199x over previous
//
#include <hip/hip_runtime.h>
#include <cstdint>
#include <cstddef>

#define DEVI __device__ __forceinline__

typedef __bf16 bf16x8 __attribute__((ext_vector_type(8)));
typedef float floatx4 __attribute__((ext_vector_type(4)));
typedef unsigned short us4v __attribute__((ext_vector_type(4)));
typedef unsigned short us8 __attribute__((ext_vector_type(8)));

static_assert(sizeof(bf16x8) == 16, "bf16x8 must be 16B");
static_assert(sizeof(us8) == 16, "us8 must be 16B");

// ---------------- helpers ----------------

#if __has_builtin(__builtin_amdgcn_cvt_pk_bf16_f32)
DEVI unsigned short f2bf(float f) {
  typedef __bf16 bf16x2 __attribute__((ext_vector_type(2)));
  union { bf16x2 v; unsigned short u[2]; } c;
  c.v = __builtin_amdgcn_cvt_pk_bf16_f32(f, 0.f);
  return c.u[0];
}
#else
DEVI unsigned short f2bf(float f) {
  unsigned int u = __float_as_uint(f);
  u += 0x7fffu + ((u >> 16) & 1u);   // RNE
  return (unsigned short)(u >> 16);
}
#endif

DEVI float exp2c(float x) {
#if __has_builtin(__builtin_amdgcn_exp2f)
  return __builtin_amdgcn_exp2f(x);
#else
  return exp2f(x);
#endif
}

DEVI bf16x8 ld8(const unsigned short* p) { return *(const bf16x8*)p; }

typedef const __attribute__((address_space(1))) void* gas_ptr;
typedef __attribute__((address_space(3))) void* las_ptr;

DEVI void gld16(const void* g, void* l) {
  __builtin_amdgcn_global_load_lds((gas_ptr)g, (las_ptr)l, 16, 0, 0);
}

#define WAIT_LGKM0() __builtin_amdgcn_s_waitcnt(0xc07f)   // lgkmcnt(0) only
#define WAIT_VM12()  __builtin_amdgcn_s_waitcnt(0x0f7c)   // vmcnt(12) only
#define WAIT_VM0()   __builtin_amdgcn_s_waitcnt(0x0f70)   // vmcnt(0) only
#define SB()         __builtin_amdgcn_sched_barrier(0)

// ---- cross-block coherent AO accesses (R10) ----
// Consumer side (the 2.1M-op volume): WIDE NON-ATOMIC sc1 load via inline asm
// (LLVM accepts 128-bit asm OUTPUTS; R9's failure was a 128-bit INPUT on the
// store). Self-contained waitcnt so the dependent LDS write can't be hoisted.
DEVI uint4 ld16_sc1(const void* p) {
  uint4 r;
  asm volatile("global_load_dwordx4 %0, %1, off sc0 sc1\n\ts_waitcnt vmcnt(0)"
               : "=v"(r) : "v"(p) : "memory");
  return r;
}
// Producer side (only ~0.5M ops): R8-verified 8B atomic sc1 stores.
DEVI void st8_sc1(unsigned long long* p, unsigned long long v) {
  __hip_atomic_store(p, v, __ATOMIC_RELAXED, __HIP_MEMORY_SCOPE_AGENT);
}

// ---------------- fused prep: mask bitpack + nodes cvt + weight transposes ----------------
// flat grid: [0,8192) pack, [8192,10240) cvt, [10240,10624) transposes (16x8x3)
__global__ __launch_bounds__(256) void prep_k(
    const float* __restrict__ nodes, const void* __restrict__ mask,
    const float* __restrict__ wq, const float* __restrict__ wkv,
    const float* __restrict__ wo,
    unsigned short* __restrict__ XB, unsigned short* __restrict__ WQKVT,
    unsigned short* __restrict__ WOT, unsigned int* __restrict__ pm) {
  int bid = blockIdx.x;
  if (bid < 8192) {
    // ---- mask pack: thread handles 4 elems; 8 threads -> one 32-bit word ----
    __shared__ int mode;
    const unsigned int* md = (const unsigned int*)mask;
    unsigned int probe = md[threadIdx.x];
    bool odd = (probe > 1u && probe != 0x3f800000u);
    if (threadIdx.x == 0) mode = 0;
    __syncthreads();
    if (odd) atomicOr(&mode, 1);
    __syncthreads();
    int byteMode = mode;
    int t = bid * 256 + threadIdx.x;
    int lane = threadIdx.x & 63;
    unsigned int n;
    if (byteMode) {
      unsigned int x = md[t];
      n = ((x & 0xffu) ? 1u : 0u) | ((x & 0xff00u) ? 2u : 0u) |
          ((x & 0xff0000u) ? 4u : 0u) | ((x >> 24) ? 8u : 0u);
    } else {
      uint4 v = ((const uint4*)mask)[t];
      n = (v.x ? 1u : 0u) | (v.y ? 2u : 0u) | (v.z ? 4u : 0u) | (v.w ? 8u : 0u);
    }
    unsigned int w = n << ((lane & 7) * 4);
    w |= __shfl_xor(w, 1);
    w |= __shfl_xor(w, 2);
    w |= __shfl_xor(w, 4);
    if ((lane & 7) == 0) pm[t >> 3] = w;
  } else if (bid < 10240) {
    // ---- nodes fp32 -> bf16 ----
    int i = (bid - 8192) * 256 + threadIdx.x;
    float4 v = ((const float4*)nodes)[i];
    us4v o;
    o[0] = f2bf(v.x); o[1] = f2bf(v.y); o[2] = f2bf(v.z); o[3] = f2bf(v.w);
    *(us4v*)(XB + (size_t)i * 4) = o;
  } else {
    // ---- weight transpose fp32 [512][C] -> bf16 dst[(c0+c)*512+k] ----
    int tb = bid - 10240;
    int x = tb & 15, y = (tb >> 4) & 7, z = tb >> 7;
    const float* src; unsigned short* dst; int C, c0;
    if (z == 0)      { if (x >= 8) return; src = wq;  dst = WQKVT; C = 512;  c0 = 0; }
    else if (z == 1) { src = wkv; dst = WQKVT; C = 1024; c0 = 512; }
    else             { if (x >= 8) return; src = wo;  dst = WOT;  C = 512;  c0 = 0; }
    __shared__ unsigned short t2[64 * 64];
    const int t = threadIdx.x;
    const int ct = x * 64, rt = y * 64;
    for (int p = 0; p < 4; p++) {
      int kl = p * 16 + (t >> 4);
      int cc = (t & 15) * 4;
      float4 v = *(const float4*)&src[(size_t)(rt + kl) * C + ct + cc];
      float f[4] = {v.x, v.y, v.z, v.w};
      for (int i = 0; i < 4; i++) {
        int c = cc + i;
        t2[c * 64 + (kl ^ (c & 56))] = f2bf(f[i]);
      }
    }
    __syncthreads();
    for (int p = 0; p < 2; p++) {
      int c = p * 32 + (t >> 3);
      int kc = (t & 7) * 8;
      us8 v = *(const us8*)&t2[c * 64 + (kc ^ (c & 56))];
      *(us8*)&dst[(size_t)(c0 + ct + c) * 512 + rt + kc] = v;
    }
  }
}

// ---------------- QKV GEMM: 64x128 tiles, grid (64,12) ----------------
__global__ __launch_bounds__(256) void gemm_qkv_k(
    const unsigned short* __restrict__ A,    // [4096][512]
    const unsigned short* __restrict__ Bt,   // [1536][512]
    const float* __restrict__ bq, const float* __restrict__ bkv,
    unsigned short* __restrict__ Qo, unsigned short* __restrict__ Ko,
    unsigned short* __restrict__ VTo) {
  __shared__ unsigned short smem[8192];
  unsigned short* sA = smem;
  unsigned short* sB = smem + 2048;
  const int tid = threadIdx.x;
  const int wave = tid >> 6, lane = tid & 63, quad = lane >> 4, l16 = lane & 15;
  const int wm = wave >> 1, wn = wave & 1;
  const int bm = blockIdx.x, bn = blockIdx.y;
  floatx4 acc[2][4] = {};
  const int arow = lane >> 2;
  const int ag = lane & 3;
  for (int kt = 0; kt < 16; kt++) {
    __syncthreads();
    {
      int rowA = wave * 16 + arow;
      int gA = ag ^ (rowA & 3);
      gld16(&A[(size_t)(bm * 64 + rowA) * 512 + kt * 32 + gA * 8], &sA[(wave * 16) * 32]);
      for (int p = 0; p < 2; p++) {
        int rowB = p * 64 + wave * 16 + arow;
        int gB = ag ^ (rowB & 3);
        gld16(&Bt[(size_t)(bn * 128 + rowB) * 512 + kt * 32 + gB * 8],
              &sB[(p * 64 + wave * 16) * 32]);
      }
    }
    __syncthreads();
    bf16x8 aF[2], bF[4];
    int swz = (quad ^ (l16 & 3)) * 8;
    for (int i = 0; i < 2; i++) aF[i] = ld8(&sA[(wm * 32 + i * 16 + l16) * 32 + swz]);
    for (int j = 0; j < 4; j++) bF[j] = ld8(&sB[(wn * 64 + j * 16 + l16) * 32 + swz]);
    for (int i = 0; i < 2; i++)
      for (int j = 0; j < 4; j++)
        acc[i][j] = __builtin_amdgcn_mfma_f32_16x16x32_bf16(aF[i], bF[j], acc[i][j], 0, 0, 0);
  }

  const int sec = bn * 2 + wn;               // 0..23: Q heads 0-7, K 8-15, V 16-23
  float bias[4];
  float scale = 1.0f;
  if (sec < 8) {
    for (int j = 0; j < 4; j++) bias[j] = bq[sec * 64 + j * 16 + l16];
    scale = 0.18033688011112042f;            // 0.125 * log2(e)
  } else {
    for (int j = 0; j < 4; j++) bias[j] = bkv[(sec - 8) * 64 + j * 16 + l16];
  }
  const int gr0 = bm * 64 + wm * 32;
  const int b = gr0 >> 11, n0 = gr0 & 2047;
  unsigned short* pw = smem + wave * 2048;
  __syncthreads();
  if (sec < 16) {
    for (int i = 0; i < 2; i++)
      for (int j = 0; j < 4; j++) {
        int cg = j * 2 + (l16 >> 3), ci = l16 & 7;
        for (int r = 0; r < 4; r++) {
          int row = i * 16 + quad * 4 + r;
          pw[row * 64 + ((cg ^ (row & 7)) * 8) + ci] = f2bf((acc[i][j][r] + bias[j]) * scale);
        }
      }
    WAIT_LGKM0();
    unsigned short* dst = (sec < 8) ? Qo + ((size_t)(b * 8 + sec) * 2048 + n0) * 64
                                    : Ko + ((size_t)(b * 8 + sec - 8) * 2048 + n0) * 64;
    for (int p = 0; p < 4; p++) {
      int row = p * 8 + (lane >> 3);
      int c8 = lane & 7;
      us8 v = *(const us8*)&pw[row * 64 + ((c8 ^ (row & 7)) * 8)];
      *(us8*)&dst[(size_t)row * 64 + c8 * 8] = v;
    }
  } else {
    // V: [64 d][32 n] s-permuted; local n = i*16 + quad*4 + r -> s = quad*8 + i*4 + r
    for (int i = 0; i < 2; i++)
      for (int j = 0; j < 4; j++) {
        int d = j * 16 + l16;
        us4v t;
        for (int r = 0; r < 4; r++) t[r] = f2bf(acc[i][j][r] + bias[j]);
        *(us4v*)&pw[d * 32 + ((quad ^ (d & 3)) * 8) + i * 4] = t;
      }
    WAIT_LGKM0();
    unsigned short* dst = VTo + (size_t)(b * 8 + sec - 16) * 64 * 2048 + n0;
    for (int p = 0; p < 4; p++) {
      int d = p * 16 + (lane >> 2);
      int c4 = lane & 3;
      us8 v = *(const us8*)&pw[d * 32 + ((c4 ^ (d & 3)) * 8)];
      *(us8*)&dst[(size_t)d * 2048 + c4 * 8] = v;
    }
  }
}

// ================= flash attention + fence-free 8-way last-arriver out GEMM =================
// Attn body verbatim R2/R8 (verified). AO written via 8B atomic sc1 stores
// (R8-verified). Rendezvous: vmcnt-drain -> relaxed fetch_add -> relaxed poll
// (R8-proven). Out chunk reads AO via WIDE NON-ATOMIC sc1 loads (the R9 fix:
// de-atomize the high-volume consumer side). 512 blocks at 2/CU.
__global__ __launch_bounds__(256, 2) void attn_out_k(
    const unsigned short* __restrict__ Q,    // [16][2048][64], pre-scaled
    const unsigned short* __restrict__ K,    // [16][2048][64]
    const unsigned short* __restrict__ Vt,   // [16][64][2048] s-permuted
    const unsigned int* __restrict__ pm,     // [2][2048][64]
    unsigned short* __restrict__ AO,         // [2][2048][512]
    const unsigned short* __restrict__ Bt,   // WOT [512][512]
    const float* __restrict__ bo, float* __restrict__ out,
    unsigned int* __restrict__ tcnt) {
  __shared__ unsigned short kv[2][4][4096];
  __shared__ float lsumB[4][64];             // 1 KB
  const int tid = threadIdx.x;
  const int wave = tid >> 6, lane = tid & 63, quad = lane >> 4, l16 = lane & 15;
  const int bh = blockIdx.x, qt = blockIdx.y, b = bh >> 3, h = bh & 7;
  const int q0 = qt * 64;
  const unsigned short* Qb = Q + (size_t)bh * 2048 * 64;
  const unsigned short* Kb = K + (size_t)bh * 2048 * 64;
  const unsigned short* Vb = Vt + (size_t)bh * 64 * 2048;
  const unsigned int* pmB = pm + (size_t)b * 2048 * 64;

  bf16x8 qF[4][2];
#pragma unroll
  for (int qb = 0; qb < 4; qb++) {
    qF[qb][0] = ld8(&Qb[(size_t)(q0 + qb * 16 + l16) * 64 + quad * 8]);
    qF[qb][1] = ld8(&Qb[(size_t)(q0 + qb * 16 + l16) * 64 + 32 + quad * 8]);
  }

  floatx4 oacc[4][4] = {};                   // [db][qb]
  floatx4 lsacc[4] = {};                     // ones-MFMA row sums, [qb]

  union { us8 u; bf16x8 v; } onesU;
#pragma unroll
  for (int i = 0; i < 8; i++) onesU.u[i] = 0x3f80;   // bf16 1.0
  const bf16x8 onesF = onesU.v;

  const int srow = lane >> 3;                // K staging: row-in-8
  const int gK = (lane & 7) ^ srow;          // K source d-group (3-bit XOR)
  const int dV = lane >> 2;                  // V staging: d-row-in-16
  const int gV = (lane & 3) ^ (dV & 3);      // V source s-group (2-bit XOR)
  const int rsw0 = quad ^ (l16 & 7);
  const int rsw1 = (4 + quad) ^ (l16 & 7);

  unsigned short* kv0 = &kv[0][wave][0];
  unsigned short* kv1 = &kv[1][wave][0];

  struct MW { unsigned int w[4]; };
  MW mwA, mwB;

  auto prefetch = [&](int it, unsigned short* dst, MW& mw) {
    const int k0w = it * 128 + wave * 32;
#pragma unroll
    for (int qb = 0; qb < 4; qb++)
      mw.w[qb] = pmB[(size_t)(q0 + qb * 16 + l16) * 64 + it * 4 + wave];
#pragma unroll
    for (int p = 0; p < 4; p++) {
      gld16(&Kb[(size_t)(k0w + p * 8 + srow) * 64 + gK * 8], dst + p * 512);
      gld16(&Vb[(size_t)(p * 16 + dV) * 2048 + k0w + gV * 8], dst + 2048 + p * 512);
    }
  };

  auto step = [&](const unsigned short* buf, const MW& mw) {
    floatx4 st[4][2];
    __builtin_amdgcn_s_setprio(1);
#pragma unroll
    for (int k2 = 0; k2 < 2; k2++) {
      const unsigned short* kr = &buf[(k2 * 16 + l16) * 64];
      bf16x8 kf0 = ld8(kr + rsw0 * 8);
      bf16x8 kf1 = ld8(kr + rsw1 * 8);
#pragma unroll
      for (int qb = 0; qb < 4; qb++) {
        floatx4 z = {0.f, 0.f, 0.f, 0.f};
        z = __builtin_amdgcn_mfma_f32_16x16x32_bf16(kf0, qF[qb][0], z, 0, 0, 0);
        st[qb][k2] = __builtin_amdgcn_mfma_f32_16x16x32_bf16(kf1, qF[qb][1], z, 0, 0, 0);
      }
    }
    __builtin_amdgcn_s_setprio(0);
    union uB { bf16x8 v; unsigned short u[8]; } pf[4];
#pragma unroll
    for (int qb = 0; qb < 4; qb++) {
      unsigned int w = mw.w[qb];
#pragma unroll
      for (int k2 = 0; k2 < 2; k2++) {
#pragma unroll
        for (int r = 0; r < 4; r++) {
          float e = exp2c(st[qb][k2][r]);
          e = ((w >> (k2 * 16 + quad * 4 + r)) & 1u) ? e : 0.f;
          pf[qb].u[k2 * 4 + r] = f2bf(e);
        }
      }
    }
    __builtin_amdgcn_s_setprio(1);
#pragma unroll
    for (int qb = 0; qb < 4; qb++)
      lsacc[qb] = __builtin_amdgcn_mfma_f32_16x16x32_bf16(onesF, pf[qb].v, lsacc[qb], 0, 0, 0);
#pragma unroll
    for (int db = 0; db < 4; db++) {
      const int d = db * 16 + l16;
      bf16x8 va = ld8(&buf[2048 + d * 32 + ((quad ^ (d & 3)) * 8)]);
#pragma unroll
      for (int qb = 0; qb < 4; qb++)
        oacc[db][qb] =
            __builtin_amdgcn_mfma_f32_16x16x32_bf16(va, pf[qb].v, oacc[db][qb], 0, 0, 0);
    }
    __builtin_amdgcn_s_setprio(0);
  };

  SB();
  prefetch(0, kv0, mwA);
  SB();
#pragma unroll 1
  for (int i = 0; i < 8; ++i) {
    prefetch(i * 2 + 1, kv1, mwB);
    SB();
    WAIT_VM12();
    SB();
    step(kv0, mwA);
    SB();
    if (i < 7) {
      prefetch(i * 2 + 2, kv0, mwA);
      SB();
      WAIT_VM12();
      SB();
    } else {
      WAIT_VM0();
      SB();
    }
    step(kv1, mwB);
    SB();
  }

  if (quad == 0) {
#pragma unroll
    for (int qb = 0; qb < 4; qb++) lsumB[wave][qb * 16 + l16] = lsacc[qb][0];
  }
  __syncthreads();                           // all waves done with kv buffers

  float* pO = (float*)&kv[0][0][0];          // 64 KB = 4 regions x 16 KB
  float* myR = pO + wave * 4096;
#pragma unroll
  for (int db = 0; db < 4; db++)
#pragma unroll
    for (int qb = 0; qb < 4; qb++) {
      int q = qb * 16 + l16;
      *(floatx4*)&myR[q * 64 + (((db * 4 + quad) ^ l16) & 15) * 4] = oacc[db][qb];
    }
  __syncthreads();
  {
    int q = tid >> 2, dblk = tid & 3;
    float inv = 1.0f / (lsumB[0][q] + lsumB[1][q] + lsumB[2][q] + lsumB[3][q]);
    float o[16];
    for (int i = 0; i < 4; i++) {
      int dg = dblk * 4 + i;
      int off = q * 64 + ((dg ^ q) & 15) * 4;
      floatx4 s = *(floatx4*)&pO[off];
      s += *(floatx4*)&pO[4096 + off];
      s += *(floatx4*)&pO[8192 + off];
      s += *(floatx4*)&pO[12288 + off];
      for (int r = 0; r < 4; r++) o[i * 4 + r] = s[r] * inv;
    }
    union { us8 v; unsigned long long q2[2]; } v0, v1;
    for (int i = 0; i < 8; i++) { v0.v[i] = f2bf(o[i]); v1.v[i] = f2bf(o[8 + i]); }
    // 8B atomic sc1 stores (R8-verified): device-visible at L3, bypass L2
    unsigned long long* dst =
        (unsigned long long*)&AO[((size_t)b * 2048 + q0 + q) * 512 + h * 64 + dblk * 16];
    st8_sc1(dst + 0, v0.q2[0]);
    st8_sc1(dst + 1, v0.q2[1]);
    st8_sc1(dst + 2, v1.q2[0]);
    st8_sc1(dst + 3, v1.q2[1]);
  }

  // ---- group rendezvous: drain sc1 stores, bump + relaxed poll to 8 ----
  WAIT_VM0();                                // own sc1 stores at coherence point
  SB();
  __syncthreads();                           // all waves' stores drained
  if (tid == 0) {
    __hip_atomic_fetch_add(&tcnt[b * 32 + qt], 1u,
                           __ATOMIC_RELAXED, __HIP_MEMORY_SCOPE_AGENT);
    while (__hip_atomic_load(&tcnt[b * 32 + qt],
                             __ATOMIC_RELAXED, __HIP_MEMORY_SCOPE_AGENT) < 8u)
      __builtin_amdgcn_s_sleep(16);
  }
  __syncthreads();                           // whole block: all 8 AO slices visible

  // ---- out chunk: this head's 64 tokens x 64 cols of the final output ----
  {
    unsigned short* sA = &kv[0][0][0];       // 4 KB  [64 tok][32 k]
    unsigned short* sB = sA + 2048;          // 4 KB  [64 col][32 k]
    const int wm = wave >> 1, wn = wave & 1;
    const int bmrow = b * 2048 + qt * 64;
    const int arow = tid >> 2;               // 0..63
    const int ag4 = tid & 3;
    const int gA = ag4 ^ (arow & 3);
    const int browB = wave * 16 + (lane >> 2);
    const int gB = (lane & 3) ^ (browB & 3);
    floatx4 acc[2][2] = {};
    for (int kt = 0; kt < 16; kt++) {
      __syncthreads();
      {
        // B: WOT rows (prior-dispatch data, normal cached gld16) -- issue first
        gld16(&Bt[(size_t)(h * 64 + browB) * 512 + kt * 32 + gB * 8],
              &sB[(wave * 16) * 32]);
        // A: AO rows via ONE wide non-atomic sc1 load each (self-draining asm)
        uint4 x = ld16_sc1(&AO[(size_t)(bmrow + arow) * 512 + kt * 32 + gA * 8]);
        *(uint4*)&sA[arow * 32 + ag4 * 8] = x;
      }
      __syncthreads();
      bf16x8 aF[2], bF[2];
      int swz = (quad ^ (l16 & 3)) * 8;
      for (int i = 0; i < 2; i++) aF[i] = ld8(&sA[(wm * 32 + i * 16 + l16) * 32 + swz]);
      for (int j = 0; j < 2; j++) bF[j] = ld8(&sB[(wn * 32 + j * 16 + l16) * 32 + swz]);
      for (int i = 0; i < 2; i++)
        for (int j = 0; j < 2; j++)
          acc[i][j] = __builtin_amdgcn_mfma_f32_16x16x32_bf16(aF[i], bF[j], acc[i][j], 0, 0, 0);
    }
    for (int i = 0; i < 2; i++)
      for (int j = 0; j < 2; j++) {
        int gc = h * 64 + wn * 32 + j * 16 + l16;
        float bb = bo[gc];
        for (int r = 0; r < 4; r++) {
          int gr = bmrow + wm * 32 + i * 16 + quad * 4 + r;
          out[(size_t)gr * 512 + gc] = acc[i][j][r] + bb;
        }
      }
  }
}

// ---------------- launch ----------------
extern "C" void kernel_launch(void* const* d_in, const int* in_sizes, int n_in,
                              void* d_out, int out_size, void* d_ws, size_t ws_size,
                              hipStream_t stream) {
  const float* nodes = (const float*)d_in[0];
  const void*  mask  = d_in[1];
  const float* wq    = (const float*)d_in[2];
  const float* bq    = (const float*)d_in[3];
  const float* wkv   = (const float*)d_in[4];
  const float* bkv   = (const float*)d_in[5];
  const float* wo    = (const float*)d_in[6];
  const float* bo    = (const float*)d_in[7];
  float* out = (float*)d_out;

  char* ws = (char*)d_ws;
  unsigned short* XB    = (unsigned short*)(ws + 0);          //  4 MB  bf16 nodes
  unsigned short* WQKVT = (unsigned short*)(ws + 4194304);    //  1.5MB
  unsigned short* WOT   = (unsigned short*)(ws + 5767168);    //  0.5MB
  unsigned short* Qm    = (unsigned short*)(ws + 6291456);    //  4 MB  [16][2048][64]
  unsigned short* Km    = (unsigned short*)(ws + 10485760);   //  4 MB
  unsigned short* VTm   = (unsigned short*)(ws + 18874368);   //  4 MB  [16][64][2048] s-perm
  unsigned short* AOm   = (unsigned short*)(ws + 23068672);   //  4 MB  [4096][512]
  unsigned int*   PM    = (unsigned int*)(ws + 27262976);     //  1 MB  packed mask
  unsigned int*   CNT   = (unsigned int*)(ws + 28311552);     //  tile counters

  (void)hipMemsetAsync(CNT, 0, 512, stream);
  prep_k<<<10624, 256, 0, stream>>>(nodes, mask, wq, wkv, wo, XB, WQKVT, WOT, PM);
  gemm_qkv_k<<<dim3(64, 12), 256, 0, stream>>>(XB, WQKVT, bq, bkv, Qm, Km, VTm);
  attn_out_k<<<dim3(16, 32), 256, 0, stream>>>(Qm, Km, VTm, PM, AOm, WOT, bo, out, CNT);
}